// Round 1
// baseline (35.947 us; speedup 1.0000x reference)
//
#include <hip/hip_runtime.h>

// PointPillarsScatter: canvas[b, :, y, x] = voxel_features[n, :]
// Shapes: voxel_features (B*N_PER, C) f32, coords (B*N_PER, 4) int (bid, 0, y, x)
// Output: (B, C, NY, NX) f32.

#define NYc 496
#define NXc 432
#define Cc  64
#define Bc  2
#define NPIX (NYc * NXc)        // 214272, divisible by 4
#define NQ   (NPIX / 4)         // 53568 float4s per (b,c) plane

// ---- Approach B: inverse-index + single coalesced gather pass ----

// Scatter point ids into the per-pixel index map (pre-memset to -1).
__global__ void pps_scatter_idx(const int* __restrict__ coords,
                                int* __restrict__ idx, int n_pts) {
    int n = blockIdx.x * blockDim.x + threadIdx.x;
    if (n >= n_pts) return;
    int bid = coords[n * 4 + 0];
    int y   = coords[n * 4 + 2];
    int x   = coords[n * 4 + 3];
    idx[bid * NPIX + y * NXc + x] = n;
}

// One coalesced pass over the whole canvas: gather-or-zero.
__global__ void pps_gather(const float* __restrict__ feat,
                           const int* __restrict__ idx,
                           float* __restrict__ out) {
    int q = blockIdx.x * blockDim.x + threadIdx.x;   // float4 index in plane
    if (q >= NQ) return;
    int plane = blockIdx.y;                          // 0 .. B*C-1
    int b = plane >> 6;                              // C == 64
    int c = plane & 63;

    const int4 pid4 = *reinterpret_cast<const int4*>(idx + (size_t)b * NPIX + (size_t)q * 4);
    float4 v;
    v.x = (pid4.x >= 0) ? feat[(size_t)pid4.x * Cc + c] : 0.0f;
    v.y = (pid4.y >= 0) ? feat[(size_t)pid4.y * Cc + c] : 0.0f;
    v.z = (pid4.z >= 0) ? feat[(size_t)pid4.z * Cc + c] : 0.0f;
    v.w = (pid4.w >= 0) ? feat[(size_t)pid4.w * Cc + c] : 0.0f;
    *reinterpret_cast<float4*>(out + (size_t)plane * NPIX + (size_t)q * 4) = v;
}

// ---- Fallback (ws too small): memset canvas + direct scatter ----

__global__ void pps_scatter_feat(const float* __restrict__ feat,
                                 const int* __restrict__ coords,
                                 float* __restrict__ out, int n_pts) {
    int t = blockIdx.x * blockDim.x + threadIdx.x;
    int n = t >> 6;           // point id
    int c = t & 63;           // channel
    if (n >= n_pts) return;
    int bid = coords[n * 4 + 0];
    int y   = coords[n * 4 + 2];
    int x   = coords[n * 4 + 3];
    out[((size_t)(bid * Cc + c)) * NPIX + (size_t)y * NXc + x] = feat[(size_t)n * Cc + c];
}

extern "C" void kernel_launch(void* const* d_in, const int* in_sizes, int n_in,
                              void* d_out, int out_size, void* d_ws, size_t ws_size,
                              hipStream_t stream) {
    const float* feat   = (const float*)d_in[0];
    const int*   coords = (const int*)d_in[1];
    float*       out    = (float*)d_out;
    int n_pts = in_sizes[1] / 4;                 // coords is (n_pts, 4)

    size_t idx_bytes = (size_t)Bc * NPIX * sizeof(int);   // 1.71 MB

    if (ws_size >= idx_bytes) {
        int* idx = (int*)d_ws;
        // 0xFF bytes -> int32 value -1 (empty pixel marker)
        hipMemsetAsync(idx, 0xFF, idx_bytes, stream);
        pps_scatter_idx<<<dim3((n_pts + 255) / 256), dim3(256), 0, stream>>>(coords, idx, n_pts);
        dim3 grid((NQ + 255) / 256, Bc * Cc);    // 210 x 128 blocks
        pps_gather<<<grid, dim3(256), 0, stream>>>(feat, idx, out);
    } else {
        hipMemsetAsync(out, 0, (size_t)out_size * sizeof(float), stream);
        long long total = (long long)n_pts * Cc;
        pps_scatter_feat<<<dim3((unsigned)((total + 255) / 256)), dim3(256), 0, stream>>>(
            feat, coords, out, n_pts);
    }
}

// Round 3
// 33.658 us; speedup vs baseline: 1.0680x; 1.0680x over previous
//
#include <hip/hip_runtime.h>

// PointPillarsScatter: canvas[b, :, y, x] = voxel_features[n, :]
// voxel_features (B*N_PER, C) f32, coords (B*N_PER, 4) int32 (bid, 0, y, x)
// Output: (B, C, NY, NX) f32.
//
// Strategy: inverse-index map (pixel -> point id) in workspace, then one
// fully-coalesced gather pass that writes every output element exactly once.

#define NYc 496
#define NXc 432
#define Cc  64
#define Bc  2
#define NPIX (NYc * NXc)        // 214272, divisible by 4
#define NQ   (NPIX / 4)         // 53568 float4 pixel-groups per plane
#define NIDX4 ((Bc * NPIX) / 4) // 107136 int4s in the idx map

typedef float f32x4 __attribute__((ext_vector_type(4)));
typedef int   i32x4 __attribute__((ext_vector_type(4)));

// Fast idx-map init to -1 (replaces slow rocclr fillBufferAligned).
__global__ void pps_init_idx(i32x4* __restrict__ idx4) {
    int i = blockIdx.x * blockDim.x + threadIdx.x;
    if (i < NIDX4) {
        i32x4 m1 = {-1, -1, -1, -1};
        idx4[i] = m1;
    }
}

// Scatter point ids into the per-pixel index map.
__global__ void pps_scatter_idx(const int* __restrict__ coords,
                                int* __restrict__ idx, int n_pts) {
    int n = blockIdx.x * blockDim.x + threadIdx.x;
    if (n >= n_pts) return;
    int bid = coords[n * 4 + 0];
    int y   = coords[n * 4 + 2];
    int x   = coords[n * 4 + 3];
    idx[bid * NPIX + y * NXc + x] = n;
}

// Coalesced gather: each thread handles 4 pixels x 4 channels.
// One float4 feat load per occupied pixel covers all 4 channels.
__global__ void pps_gather4(const float* __restrict__ feat,
                            const int* __restrict__ idx,
                            float* __restrict__ out) {
    int q = blockIdx.x * blockDim.x + threadIdx.x;   // float4 pixel-group
    if (q >= NQ) return;
    int g  = blockIdx.y;                             // 0..31 plane group
    int b  = g >> 4;                                 // 16 groups of 4 ch per b
    int c0 = (g & 15) << 2;                          // starting channel

    const i32x4 pid4 = *reinterpret_cast<const i32x4*>(idx + (size_t)b * NPIX + (size_t)q * 4);

    f32x4 zero = {0.f, 0.f, 0.f, 0.f};
    f32x4 f0 = zero, f1 = zero, f2 = zero, f3 = zero;
    if (pid4.x >= 0) f0 = *reinterpret_cast<const f32x4*>(feat + (size_t)pid4.x * Cc + c0);
    if (pid4.y >= 0) f1 = *reinterpret_cast<const f32x4*>(feat + (size_t)pid4.y * Cc + c0);
    if (pid4.z >= 0) f2 = *reinterpret_cast<const f32x4*>(feat + (size_t)pid4.z * Cc + c0);
    if (pid4.w >= 0) f3 = *reinterpret_cast<const f32x4*>(feat + (size_t)pid4.w * Cc + c0);

    // Transpose: plane j gets component j of each pixel's feature vector.
    f32x4 o0 = {f0.x, f1.x, f2.x, f3.x};
    f32x4 o1 = {f0.y, f1.y, f2.y, f3.y};
    f32x4 o2 = {f0.z, f1.z, f2.z, f3.z};
    f32x4 o3 = {f0.w, f1.w, f2.w, f3.w};

    size_t base = ((size_t)(b * Cc + c0)) * NPIX + (size_t)q * 4;
    __builtin_nontemporal_store(o0, reinterpret_cast<f32x4*>(out + base));
    __builtin_nontemporal_store(o1, reinterpret_cast<f32x4*>(out + base + (size_t)NPIX));
    __builtin_nontemporal_store(o2, reinterpret_cast<f32x4*>(out + base + (size_t)2 * NPIX));
    __builtin_nontemporal_store(o3, reinterpret_cast<f32x4*>(out + base + (size_t)3 * NPIX));
}

// ---- Fallback (ws too small): memset canvas + direct scatter ----

__global__ void pps_scatter_feat(const float* __restrict__ feat,
                                 const int* __restrict__ coords,
                                 float* __restrict__ out, int n_pts) {
    int t = blockIdx.x * blockDim.x + threadIdx.x;
    int n = t >> 6;           // point id
    int c = t & 63;           // channel
    if (n >= n_pts) return;
    int bid = coords[n * 4 + 0];
    int y   = coords[n * 4 + 2];
    int x   = coords[n * 4 + 3];
    out[((size_t)(bid * Cc + c)) * NPIX + (size_t)y * NXc + x] = feat[(size_t)n * Cc + c];
}

extern "C" void kernel_launch(void* const* d_in, const int* in_sizes, int n_in,
                              void* d_out, int out_size, void* d_ws, size_t ws_size,
                              hipStream_t stream) {
    const float* feat   = (const float*)d_in[0];
    const int*   coords = (const int*)d_in[1];
    float*       out    = (float*)d_out;
    int n_pts = in_sizes[1] / 4;                 // coords is (n_pts, 4)

    size_t idx_bytes = (size_t)Bc * NPIX * sizeof(int);   // 1.71 MB

    if (ws_size >= idx_bytes) {
        int* idx = (int*)d_ws;
        pps_init_idx<<<dim3((NIDX4 + 255) / 256), dim3(256), 0, stream>>>((i32x4*)idx);
        pps_scatter_idx<<<dim3((n_pts + 255) / 256), dim3(256), 0, stream>>>(coords, idx, n_pts);
        dim3 grid((NQ + 255) / 256, (Bc * Cc) / 4);       // 210 x 32 blocks
        pps_gather4<<<grid, dim3(256), 0, stream>>>(feat, idx, out);
    } else {
        (void)hipMemsetAsync(out, 0, (size_t)out_size * sizeof(float), stream);
        long long total = (long long)n_pts * Cc;
        pps_scatter_feat<<<dim3((unsigned)((total + 255) / 256)), dim3(256), 0, stream>>>(
            feat, coords, out, n_pts);
    }
}